// Round 4
// baseline (1731.926 us; speedup 1.0000x reference)
//
#include <hip/hip_runtime.h>
#include <hip/hip_bf16.h>
#include <cstdint>

typedef float  f32x4  __attribute__((ext_vector_type(4)));
typedef __bf16 bf16x8 __attribute__((ext_vector_type(8)));
typedef __bf16 bf16x4 __attribute__((ext_vector_type(4)));
typedef __bf16 bf16x2 __attribute__((ext_vector_type(2)));

#define AS1 __attribute__((address_space(1)))
#define AS3 __attribute__((address_space(3)))

static constexpr int D   = 4096;
static constexpr int SEQ = 2048;
static constexpr int MX  = 4224;   // padded rows: 4096 x-rows + 10 adapter + pad

__device__ __forceinline__ void gload_lds16(const void* g, void* l) {
  __builtin_amdgcn_global_load_lds((AS1 void*)(g), (AS3 void*)(l), 16, 0, 0);
}

__device__ __forceinline__ f32x4 mfma16(bf16x8 a, bf16x8 b, f32x4 c) {
  return __builtin_amdgcn_mfma_f32_16x16x32_bf16(a, b, c, 0, 0, 0);
}

// ---------------------------------------------------------------------------
// transpose + cast: W (f32, K x N row-major) -> WT (bf16, N x K row-major)
__global__ __launch_bounds__(256) void transpose_cast(const float* __restrict__ W,
                                                      __bf16* __restrict__ WT) {
  __shared__ float tile[64][65];
  const int t  = threadIdx.x;
  const int r0 = blockIdx.x * 64;   // K index
  const int c0 = blockIdx.y * 64;   // N index
#pragma unroll
  for (int p = 0; p < 4; ++p) {
    int e = p * 1024 + t * 4;
    int row = e >> 6, col = e & 63;
    f32x4 v = *(const f32x4*)(W + (size_t)(r0 + row) * D + c0 + col);
#pragma unroll
    for (int i = 0; i < 4; ++i) tile[row][col + i] = v[i];
  }
  __syncthreads();
#pragma unroll
  for (int p = 0; p < 2; ++p) {
    int e = p * 2048 + t * 8;
    int orow = e >> 6, ocol = e & 63;
    bf16x8 o;
#pragma unroll
    for (int i = 0; i < 8; ++i) o[i] = (__bf16)tile[ocol + i][orow];
    *(bf16x8*)(WT + (size_t)(c0 + orow) * D + r0 + ocol) = o;
  }
}

// ---------------------------------------------------------------------------
// build xa (bf16, MX x D): rows 0..4095 = x, 4096..4105 = adapter, rest 0
__global__ __launch_bounds__(256) void build_xa(const float* __restrict__ x,
                                                const float* __restrict__ ad,
                                                __bf16* __restrict__ xa) {
  int idx = blockIdx.x * 256 + threadIdx.x;
  int e = idx * 4;
  int row = e >> 12, col = e & 4095;
  f32x4 v = {};
  if (row < 4096)      v = *(const f32x4*)(x + (size_t)row * D + col);
  else if (row < 4106) v = *(const f32x4*)(ad + (size_t)(row - 4096) * D + col);
  bf16x4 o;
#pragma unroll
  for (int i = 0; i < 4; ++i) o[i] = (__bf16)v[i];
  *(bf16x4*)(xa + (size_t)row * D + col) = o;
}

// ---------------------------------------------------------------------------
// GEMM: C[M x 4096] = A[M x 4096] * B, with B given transposed (BT: N x K).
// 128x128 tile, BK=64, 4 waves (2x2), 16x16x32 bf16 MFMA. m97 structure.
template <bool F32OUT>
__global__ __launch_bounds__(256) void gemm_bt(const __bf16* __restrict__ A,
                                               const __bf16* __restrict__ BT,
                                               void* __restrict__ Cout) {
  __shared__ __bf16 As[128 * 64];
  __shared__ __bf16 Bs[128 * 64];
  const int tid = threadIdx.x;
  const int wv = tid >> 6, ln = tid & 63;
  const int lg = ln >> 4, lr = ln & 15;
  const int m0 = blockIdx.x * 128, n0 = blockIdx.y * 128;
  const int wm = (wv >> 1) * 64, wn = (wv & 1) * 64;

  f32x4 acc[4][4] = {};
  const __bf16* Ab = A + (size_t)m0 * D;
  const __bf16* Bb = BT + (size_t)n0 * D;

  for (int kt = 0; kt < D; kt += 64) {
#pragma unroll
    for (int j = 0; j < 4; ++j) {
      int c = wv * 256 + j * 64 + ln;
      int r = c >> 3, cb = c & 7;
      int sc = cb ^ (r & 7);
      gload_lds16(Ab + (size_t)r * D + kt + sc * 8, As + (wv * 256 + j * 64) * 8);
      gload_lds16(Bb + (size_t)r * D + kt + sc * 8, Bs + (wv * 256 + j * 64) * 8);
    }
    __syncthreads();
#pragma unroll
    for (int kk = 0; kk < 2; ++kk) {
      bf16x8 af[4], bfr[4];
#pragma unroll
      for (int i = 0; i < 4; ++i) {
        int ar = wm + i * 16 + lr;
        af[i] = *(const bf16x8*)(As + ar * 64 + (((kk * 4 + lg) ^ (ar & 7)) * 8));
        int br = wn + i * 16 + lr;
        bfr[i] = *(const bf16x8*)(Bs + br * 64 + (((kk * 4 + lg) ^ (br & 7)) * 8));
      }
#pragma unroll
      for (int mi = 0; mi < 4; ++mi)
#pragma unroll
        for (int ni = 0; ni < 4; ++ni)
          acc[mi][ni] = mfma16(af[mi], bfr[ni], acc[mi][ni]);
    }
    __syncthreads();
  }

#pragma unroll
  for (int mi = 0; mi < 4; ++mi)
#pragma unroll
    for (int ni = 0; ni < 4; ++ni)
#pragma unroll
      for (int j = 0; j < 4; ++j) {
        int row = m0 + wm + mi * 16 + lg * 4 + j;
        int col = n0 + wn + ni * 16 + lr;
        if constexpr (F32OUT)
          ((float*)Cout)[(size_t)row * D + col] = acc[mi][ni][j];
        else
          ((__bf16*)Cout)[(size_t)row * D + col] = (__bf16)acc[mi][ni][j];
      }
}

// ---------------------------------------------------------------------------
// RoPE in-place on q (4096 rows) and k (first 4096 rows). freqs are f32 tables.
__global__ __launch_bounds__(256) void rope_kernel(__bf16* __restrict__ q,
                                                   __bf16* __restrict__ k,
                                                   const float* __restrict__ fc,
                                                   const float* __restrict__ fs) {
  int row = blockIdx.x;
  __bf16* buf = blockIdx.y ? k : q;
  int t = threadIdx.x;
  int s = row & (SEQ - 1);
  int jb = (t & 7) * 8;
  const float* cp = fc + s * 64 + jb;
  const float* sp = fs + s * 64 + jb;
  __bf16* p = buf + (size_t)row * D + t * 16;
  bf16x8 v0 = *(const bf16x8*)p;
  bf16x8 v1 = *(const bf16x8*)(p + 8);
  bf16x8 o0, o1;
#pragma unroll
  for (int i = 0; i < 4; ++i) {
    float C = cp[i], Sn = sp[i];
    float re = (float)v0[2 * i], im = (float)v0[2 * i + 1];
    o0[2 * i]     = (__bf16)(re * C - im * Sn);
    o0[2 * i + 1] = (__bf16)(re * Sn + im * C);
  }
#pragma unroll
  for (int i = 0; i < 4; ++i) {
    float C = cp[4 + i], Sn = sp[4 + i];
    float re = (float)v1[2 * i], im = (float)v1[2 * i + 1];
    o1[2 * i]     = (__bf16)(re * C - im * Sn);
    o1[2 * i + 1] = (__bf16)(re * Sn + im * C);
  }
  *(bf16x8*)p = o0;
  *(bf16x8*)(p + 8) = o1;
}

// ---------------------------------------------------------------------------
// transpose V (MX x 4096 bf16) -> VT (4096 x MX bf16)
__global__ __launch_bounds__(256) void transpose_v(const __bf16* __restrict__ V,
                                                   __bf16* __restrict__ VT) {
  __shared__ __bf16 tile[64][72];
  const int t  = threadIdx.x;
  const int r0 = blockIdx.x * 64;   // V row (kv)
  const int c0 = blockIdx.y * 64;   // V col (dim)
#pragma unroll
  for (int p = 0; p < 2; ++p) {
    int e = p * 2048 + t * 8;
    int row = e >> 6, col = e & 63;
    bf16x8 v8 = *(const bf16x8*)(V + (size_t)(r0 + row) * D + c0 + col);
#pragma unroll
    for (int i = 0; i < 8; ++i) tile[row][col + i] = v8[i];
  }
  __syncthreads();
#pragma unroll
  for (int p = 0; p < 2; ++p) {
    int e = p * 2048 + t * 8;
    int orow = e >> 6, ocol = e & 63;
    bf16x8 o;
#pragma unroll
    for (int i = 0; i < 8; ++i) o[i] = tile[ocol + i][orow];
    *(bf16x8*)(VT + (size_t)(c0 + orow) * MX + r0 + ocol) = o;
  }
}

// ---------------------------------------------------------------------------
// Flash attention + adapter. Barrier-free: no K/V LDS staging (fragments read
// directly from global; L1/L2 serve reuse), swapped QK^T (S^T = K*Q^T) so the
// softmax row lives in-lane (15 in-lane ops + 2 shfl levels instead of 4-level
// chains). Per-wave P relayout via small LDS (no cross-wave sync).
// grid: (16 qtiles, 32 heads, 2 batch); 256 threads = 4 independent waves.
__global__ __launch_bounds__(256) void attn_kernel(const __bf16* __restrict__ Q,
                                                   const __bf16* __restrict__ K,
                                                   const __bf16* __restrict__ VT,
                                                   const float* __restrict__ gate,
                                                   __bf16* __restrict__ Out) {
  __shared__ __bf16 Ps[4][32 * 64];    // per-wave P, swizzled 8-elem chunks

  const int tid = threadIdx.x;
  const int wv = tid >> 6, ln = tid & 63;
  const int lg = ln >> 4, lr = ln & 15;
  const int qt = 15 - blockIdx.x;      // heavy tiles first
  const int h = blockIdx.y, b = blockIdx.z;
  const int q0 = qt * 128;
  const int qbase = b * SEQ + q0 + wv * 32;
  const float scale = 0.08838834764831845f;   // 1/sqrt(128)

  // Q fragments (B-operand layout == A-operand layout): [mi][kd]
  bf16x8 qf[2][4];
#pragma unroll
  for (int mi = 0; mi < 2; ++mi)
#pragma unroll
    for (int kd = 0; kd < 4; ++kd)
      qf[mi][kd] = *(const bf16x8*)(Q + (size_t)(qbase + mi * 16 + lr) * D +
                                    h * 128 + kd * 32 + lg * 8);

  f32x4 O[2][8] = {};
  float mI2[2], lI2[2];                // stats for q = mi*16 + lr (this lane)
#pragma unroll
  for (int mi = 0; mi < 2; ++mi) { mI2[mi] = -1e30f; lI2[mi] = 0.f; }

  const int ntiles = 2 * qt + 2;
  for (int t = 0; t < ntiles; ++t) {
    const int kv0 = t * 64;

    // ---- QK^T, swapped: S[mi][nf] = S^T fragment.
    // lane holds q = mi*16+lr (col), kv = kv0 + nf*16 + lg*4 + j (row j).
    f32x4 S[2][4] = {};
    __builtin_amdgcn_s_setprio(1);
#pragma unroll
    for (int kd = 0; kd < 4; ++kd) {
      bf16x8 kf[4];
#pragma unroll
      for (int nf = 0; nf < 4; ++nf)
        kf[nf] = *(const bf16x8*)(K + (size_t)(b * SEQ + kv0 + nf * 16 + lr) * D +
                                  h * 128 + kd * 32 + lg * 8);
#pragma unroll
      for (int mi = 0; mi < 2; ++mi)
#pragma unroll
        for (int nf = 0; nf < 4; ++nf)
          S[mi][nf] = mfma16(kf[nf], qf[mi][kd], S[mi][nf]);
    }
    __builtin_amdgcn_s_setprio(0);

    // ---- softmax (mostly in-lane)
    float r2[2]; int grew = 0;
#pragma unroll
    for (int mi = 0; mi < 2; ++mi) {
      const int qg = q0 + wv * 32 + mi * 16 + lr;
      float mo = mI2[mi];
      float mt = -3e38f;
#pragma unroll
      for (int nf = 0; nf < 4; ++nf)
#pragma unroll
        for (int j = 0; j < 4; ++j) {
          int kvg = kv0 + nf * 16 + lg * 4 + j;
          float s = S[mi][nf][j] * scale;
          s = (kvg > qg) ? -1e30f : s;
          S[mi][nf][j] = s;
          mt = fmaxf(mt, s);
        }
      mt = fmaxf(mt, __shfl_xor(mt, 16));
      mt = fmaxf(mt, __shfl_xor(mt, 32));
      float mn = fmaxf(mo, mt);
      float ps = 0.f;
#pragma unroll
      for (int nf = 0; nf < 4; ++nf)
#pragma unroll
        for (int j = 0; j < 4; ++j) {
          float p = __expf(S[mi][nf][j] - mn);
          S[mi][nf][j] = p;
          ps += p;
        }
      ps += __shfl_xor(ps, 16);
      ps += __shfl_xor(ps, 32);
      float r = __expf(mo - mn);       // == 1.0f when max unchanged
      lI2[mi] = lI2[mi] * r + ps;
      mI2[mi] = mn;
      r2[mi] = r;
      grew |= (mn > mo) ? 1 : 0;
    }
    if (__any(grew)) {                 // wave-uniform rescale skip
#pragma unroll
      for (int mi = 0; mi < 2; ++mi)
#pragma unroll
        for (int j = 0; j < 4; ++j) {
          float rj = __shfl(r2[mi], lg * 4 + j);
#pragma unroll
          for (int n = 0; n < 8; ++n) O[mi][n][j] *= rj;
        }
    }

    // ---- P -> bf16 pairs -> per-wave LDS (swizzled), no barrier needed
#pragma unroll
    for (int mi = 0; mi < 2; ++mi) {
      int q = mi * 16 + lr;
#pragma unroll
      for (int nf = 0; nf < 4; ++nf)
#pragma unroll
        for (int jj = 0; jj < 2; ++jj) {
          int kv = nf * 16 + lg * 4 + 2 * jj;
          bf16x2 pk;
          pk[0] = (__bf16)S[mi][nf][2 * jj];
          pk[1] = (__bf16)S[mi][nf][2 * jj + 1];
          *(bf16x2*)(Ps[wv] + q * 64 + (((kv >> 3) ^ (q & 7)) * 8) + (kv & 7)) = pk;
        }
    }

    // ---- PV
    __builtin_amdgcn_s_setprio(1);
#pragma unroll
    for (int kkv = 0; kkv < 2; ++kkv) {
      bf16x8 pf[2];
#pragma unroll
      for (int mi = 0; mi < 2; ++mi) {
        int prw = mi * 16 + lr;
        pf[mi] = *(const bf16x8*)(Ps[wv] + prw * 64 + (((kkv * 4 + lg) ^ (prw & 7)) * 8));
      }
#pragma unroll
      for (int n = 0; n < 8; ++n) {
        bf16x8 vf = *(const bf16x8*)(VT + (size_t)(h * 128 + n * 16 + lr) * MX +
                                     b * SEQ + kv0 + kkv * 32 + lg * 8);
#pragma unroll
        for (int mi = 0; mi < 2; ++mi) O[mi][n] = mfma16(pf[mi], vf, O[mi][n]);
      }
    }
    __builtin_amdgcn_s_setprio(0);
  }

  // ---- normalize (distribute 1/l from q=lr lanes to q=lg*4+j positions)
#pragma unroll
  for (int mi = 0; mi < 2; ++mi) {
    float inv = 1.0f / lI2[mi];
#pragma unroll
    for (int j = 0; j < 4; ++j) {
      float invj = __shfl(inv, lg * 4 + j);
#pragma unroll
      for (int n = 0; n < 8; ++n) O[mi][n][j] *= invj;
    }
  }

  // ---- adapter branch (10 kv rows at 4096..; rows 4106..4111 are zero-pad)
  {
    f32x4 Sa[2] = {};
    __builtin_amdgcn_s_setprio(1);
#pragma unroll
    for (int kd = 0; kd < 4; ++kd) {
      bf16x8 kfa = *(const bf16x8*)(K + (size_t)(2 * SEQ + lr) * D +
                                    h * 128 + kd * 32 + lg * 8);
#pragma unroll
      for (int mi = 0; mi < 2; ++mi) Sa[mi] = mfma16(kfa, qf[mi][kd], Sa[mi]);
    }
    __builtin_amdgcn_s_setprio(0);

    float g = tanhf(gate[h]);
#pragma unroll
    for (int mi = 0; mi < 2; ++mi) {
      float mt = -3e38f;
#pragma unroll
      for (int j = 0; j < 4; ++j) {
        int kv = lg * 4 + j;
        float s = Sa[mi][j] * scale;
        s = (kv >= 10) ? -1e30f : s;
        Sa[mi][j] = s;
        mt = fmaxf(mt, s);
      }
      mt = fmaxf(mt, __shfl_xor(mt, 16));
      mt = fmaxf(mt, __shfl_xor(mt, 32));
      float ps = 0.f;
#pragma unroll
      for (int j = 0; j < 4; ++j) {
        float p = __expf(Sa[mi][j] - mt);
        Sa[mi][j] = p;
        ps += p;
      }
      ps += __shfl_xor(ps, 16);
      ps += __shfl_xor(ps, 32);
      float gs = g / ps;
      int q = mi * 16 + lr;
#pragma unroll
      for (int jj = 0; jj < 2; ++jj) {
        int kv = lg * 4 + 2 * jj;
        bf16x2 pk;
        pk[0] = (__bf16)(Sa[mi][2 * jj] * gs);
        pk[1] = (__bf16)(Sa[mi][2 * jj + 1] * gs);
        *(bf16x2*)(Ps[wv] + q * 64 + (((kv >> 3) ^ (q & 7)) * 8) + (kv & 7)) = pk;
        int kv2 = 16 + kv;
        bf16x2 z = {};
        *(bf16x2*)(Ps[wv] + q * 64 + (((kv2 >> 3) ^ (q & 7)) * 8) + (kv2 & 7)) = z;
      }
    }
    bf16x8 pfa[2];
#pragma unroll
    for (int mi = 0; mi < 2; ++mi) {
      int prw = mi * 16 + lr;
      pfa[mi] = *(const bf16x8*)(Ps[wv] + prw * 64 + ((lg ^ (prw & 7)) * 8));
    }
#pragma unroll
    for (int n = 0; n < 8; ++n) {
      bf16x8 vfa = *(const bf16x8*)(VT + (size_t)(h * 128 + n * 16 + lr) * MX +
                                    2 * SEQ + lg * 8);
#pragma unroll
      for (int mi = 0; mi < 2; ++mi) O[mi][n] = mfma16(pfa[mi], vfa, O[mi][n]);
    }
  }

  // ---- write out
#pragma unroll
  for (int mi = 0; mi < 2; ++mi)
#pragma unroll
    for (int n = 0; n < 8; ++n)
#pragma unroll
      for (int j = 0; j < 4; ++j)
        Out[(size_t)(qbase + mi * 16 + lg * 4 + j) * D + h * 128 + n * 16 + lr] =
            (__bf16)O[mi][n][j];
}

// ---------------------------------------------------------------------------
extern "C" void kernel_launch(void* const* d_in, const int* in_sizes, int n_in,
                              void* d_out, int out_size, void* d_ws, size_t ws_size,
                              hipStream_t stream) {
  const float* x    = (const float*)d_in[0];
  const float* wq   = (const float*)d_in[1];
  const float* wk   = (const float*)d_in[2];
  const float* wv   = (const float*)d_in[3];
  const float* wo   = (const float*)d_in[4];
  const float* gate = (const float*)d_in[5];
  const float* ad   = (const float*)d_in[6];
  const float* fc   = (const float*)d_in[7];
  const float* fs   = (const float*)d_in[8];

  const size_t WSZ = (size_t)D * D * 2;     // 33,554,432
  const size_t XSZ = (size_t)MX * D * 2;    // 34,603,008
  if (ws_size < 4 * WSZ + XSZ + WSZ + 3 * XSZ) return;  // 306,184,192 needed

  char* w = (char*)d_ws;
  size_t off = 0;
  auto alloc = [&](size_t sz) { void* p = w + off; off += sz; return p; };
  __bf16* wqT = (__bf16*)alloc(WSZ);
  __bf16* wkT = (__bf16*)alloc(WSZ);
  __bf16* wvT = (__bf16*)alloc(WSZ);
  __bf16* woT = (__bf16*)alloc(WSZ);
  __bf16* xa  = (__bf16*)alloc(XSZ);
  __bf16* qb  = (__bf16*)alloc(WSZ);
  __bf16* kb  = (__bf16*)alloc(XSZ);
  __bf16* vb  = (__bf16*)alloc(XSZ);
  __bf16* vT  = (__bf16*)alloc(XSZ);
  __bf16* attn = vb;   // vb dead after transpose_v; reuse as attention output

  dim3 blk(256);
  transpose_cast<<<dim3(64, 64), blk, 0, stream>>>(wq, wqT);
  transpose_cast<<<dim3(64, 64), blk, 0, stream>>>(wk, wkT);
  transpose_cast<<<dim3(64, 64), blk, 0, stream>>>(wv, wvT);
  transpose_cast<<<dim3(64, 64), blk, 0, stream>>>(wo, woT);
  build_xa<<<dim3(16896), blk, 0, stream>>>(x, ad, xa);

  gemm_bt<false><<<dim3(32, 32), blk, 0, stream>>>(xa, wqT, qb);
  gemm_bt<false><<<dim3(33, 32), blk, 0, stream>>>(xa, wkT, kb);
  gemm_bt<false><<<dim3(33, 32), blk, 0, stream>>>(xa, wvT, vb);

  rope_kernel<<<dim3(4096, 2), blk, 0, stream>>>(qb, kb, fc, fs);
  transpose_v<<<dim3(66, 64), blk, 0, stream>>>(vb, vT);

  attn_kernel<<<dim3(16, 32, 2), blk, 0, stream>>>(qb, kb, vT, gate, attn);

  gemm_bt<true><<<dim3(32, 32), blk, 0, stream>>>(attn, woT, d_out);
}

// Round 5
// 1204.366 us; speedup vs baseline: 1.4380x; 1.4380x over previous
//
#include <hip/hip_runtime.h>
#include <hip/hip_bf16.h>
#include <cstdint>

typedef float  f32x4  __attribute__((ext_vector_type(4)));
typedef __bf16 bf16x8 __attribute__((ext_vector_type(8)));
typedef __bf16 bf16x4 __attribute__((ext_vector_type(4)));
typedef __bf16 bf16x2 __attribute__((ext_vector_type(2)));

#define AS1 __attribute__((address_space(1)))
#define AS3 __attribute__((address_space(3)))

static constexpr int D   = 4096;
static constexpr int SEQ = 2048;
static constexpr int MX  = 4224;   // padded rows: 4096 x-rows + 10 adapter + pad

__device__ __forceinline__ void gload_lds16(const void* g, void* l) {
  __builtin_amdgcn_global_load_lds((AS1 void*)(g), (AS3 void*)(l), 16, 0, 0);
}

__device__ __forceinline__ f32x4 mfma16(bf16x8 a, bf16x8 b, f32x4 c) {
  return __builtin_amdgcn_mfma_f32_16x16x32_bf16(a, b, c, 0, 0, 0);
}

// ---------------------------------------------------------------------------
// transpose + cast: W (f32, K x N row-major) -> WT (bf16, N x K row-major)
__global__ __launch_bounds__(256) void transpose_cast(const float* __restrict__ W,
                                                      __bf16* __restrict__ WT) {
  __shared__ float tile[64][65];
  const int t  = threadIdx.x;
  const int r0 = blockIdx.x * 64;   // K index
  const int c0 = blockIdx.y * 64;   // N index
#pragma unroll
  for (int p = 0; p < 4; ++p) {
    int e = p * 1024 + t * 4;
    int row = e >> 6, col = e & 63;
    f32x4 v = *(const f32x4*)(W + (size_t)(r0 + row) * D + c0 + col);
#pragma unroll
    for (int i = 0; i < 4; ++i) tile[row][col + i] = v[i];
  }
  __syncthreads();
#pragma unroll
  for (int p = 0; p < 2; ++p) {
    int e = p * 2048 + t * 8;
    int orow = e >> 6, ocol = e & 63;
    bf16x8 o;
#pragma unroll
    for (int i = 0; i < 8; ++i) o[i] = (__bf16)tile[ocol + i][orow];
    *(bf16x8*)(WT + (size_t)(c0 + orow) * D + r0 + ocol) = o;
  }
}

// ---------------------------------------------------------------------------
// build xa (bf16, MX x D): rows 0..4095 = x, 4096..4105 = adapter, rest 0
__global__ __launch_bounds__(256) void build_xa(const float* __restrict__ x,
                                                const float* __restrict__ ad,
                                                __bf16* __restrict__ xa) {
  int idx = blockIdx.x * 256 + threadIdx.x;
  int e = idx * 4;
  int row = e >> 12, col = e & 4095;
  f32x4 v = {};
  if (row < 4096)      v = *(const f32x4*)(x + (size_t)row * D + col);
  else if (row < 4106) v = *(const f32x4*)(ad + (size_t)(row - 4096) * D + col);
  bf16x4 o;
#pragma unroll
  for (int i = 0; i < 4; ++i) o[i] = (__bf16)v[i];
  *(bf16x4*)(xa + (size_t)row * D + col) = o;
}

// ---------------------------------------------------------------------------
// GEMM: C[M x 4096] = A[M x 4096] * B, with B given transposed (BT: N x K).
// 128x128 tile, BK=64, 4 waves (2x2), 16x16x32 bf16 MFMA. m97 structure.
template <bool F32OUT>
__global__ __launch_bounds__(256) void gemm_bt(const __bf16* __restrict__ A,
                                               const __bf16* __restrict__ BT,
                                               void* __restrict__ Cout) {
  __shared__ __bf16 As[128 * 64];
  __shared__ __bf16 Bs[128 * 64];
  const int tid = threadIdx.x;
  const int wv = tid >> 6, ln = tid & 63;
  const int lg = ln >> 4, lr = ln & 15;
  const int m0 = blockIdx.x * 128, n0 = blockIdx.y * 128;
  const int wm = (wv >> 1) * 64, wn = (wv & 1) * 64;

  f32x4 acc[4][4] = {};
  const __bf16* Ab = A + (size_t)m0 * D;
  const __bf16* Bb = BT + (size_t)n0 * D;

  for (int kt = 0; kt < D; kt += 64) {
#pragma unroll
    for (int j = 0; j < 4; ++j) {
      int c = wv * 256 + j * 64 + ln;
      int r = c >> 3, cb = c & 7;
      int sc = cb ^ (r & 7);
      gload_lds16(Ab + (size_t)r * D + kt + sc * 8, As + (wv * 256 + j * 64) * 8);
      gload_lds16(Bb + (size_t)r * D + kt + sc * 8, Bs + (wv * 256 + j * 64) * 8);
    }
    __syncthreads();
#pragma unroll
    for (int kk = 0; kk < 2; ++kk) {
      bf16x8 af[4], bfr[4];
#pragma unroll
      for (int i = 0; i < 4; ++i) {
        int ar = wm + i * 16 + lr;
        af[i] = *(const bf16x8*)(As + ar * 64 + (((kk * 4 + lg) ^ (ar & 7)) * 8));
        int br = wn + i * 16 + lr;
        bfr[i] = *(const bf16x8*)(Bs + br * 64 + (((kk * 4 + lg) ^ (br & 7)) * 8));
      }
#pragma unroll
      for (int mi = 0; mi < 4; ++mi)
#pragma unroll
        for (int ni = 0; ni < 4; ++ni)
          acc[mi][ni] = mfma16(af[mi], bfr[ni], acc[mi][ni]);
    }
    __syncthreads();
  }

#pragma unroll
  for (int mi = 0; mi < 4; ++mi)
#pragma unroll
    for (int ni = 0; ni < 4; ++ni)
#pragma unroll
      for (int j = 0; j < 4; ++j) {
        int row = m0 + wm + mi * 16 + lg * 4 + j;
        int col = n0 + wn + ni * 16 + lr;
        if constexpr (F32OUT)
          ((float*)Cout)[(size_t)row * D + col] = acc[mi][ni][j];
        else
          ((__bf16*)Cout)[(size_t)row * D + col] = (__bf16)acc[mi][ni][j];
      }
}

// ---------------------------------------------------------------------------
// RoPE in-place on q (4096 rows) and k (first 4096 rows). freqs are f32 tables.
__global__ __launch_bounds__(256) void rope_kernel(__bf16* __restrict__ q,
                                                   __bf16* __restrict__ k,
                                                   const float* __restrict__ fc,
                                                   const float* __restrict__ fs) {
  int row = blockIdx.x;
  __bf16* buf = blockIdx.y ? k : q;
  int t = threadIdx.x;
  int s = row & (SEQ - 1);
  int jb = (t & 7) * 8;
  const float* cp = fc + s * 64 + jb;
  const float* sp = fs + s * 64 + jb;
  __bf16* p = buf + (size_t)row * D + t * 16;
  bf16x8 v0 = *(const bf16x8*)p;
  bf16x8 v1 = *(const bf16x8*)(p + 8);
  bf16x8 o0, o1;
#pragma unroll
  for (int i = 0; i < 4; ++i) {
    float C = cp[i], Sn = sp[i];
    float re = (float)v0[2 * i], im = (float)v0[2 * i + 1];
    o0[2 * i]     = (__bf16)(re * C - im * Sn);
    o0[2 * i + 1] = (__bf16)(re * Sn + im * C);
  }
#pragma unroll
  for (int i = 0; i < 4; ++i) {
    float C = cp[4 + i], Sn = sp[4 + i];
    float re = (float)v1[2 * i], im = (float)v1[2 * i + 1];
    o1[2 * i]     = (__bf16)(re * C - im * Sn);
    o1[2 * i + 1] = (__bf16)(re * Sn + im * C);
  }
  *(bf16x8*)p = o0;
  *(bf16x8*)(p + 8) = o1;
}

// ---------------------------------------------------------------------------
// transpose V (MX x 4096 bf16) -> VT (4096 x MX bf16)
__global__ __launch_bounds__(256) void transpose_v(const __bf16* __restrict__ V,
                                                   __bf16* __restrict__ VT) {
  __shared__ __bf16 tile[64][72];
  const int t  = threadIdx.x;
  const int r0 = blockIdx.x * 64;   // V row (kv)
  const int c0 = blockIdx.y * 64;   // V col (dim)
#pragma unroll
  for (int p = 0; p < 2; ++p) {
    int e = p * 2048 + t * 8;
    int row = e >> 6, col = e & 63;
    bf16x8 v8 = *(const bf16x8*)(V + (size_t)(r0 + row) * D + c0 + col);
#pragma unroll
    for (int i = 0; i < 8; ++i) tile[row][col + i] = v8[i];
  }
  __syncthreads();
#pragma unroll
  for (int p = 0; p < 2; ++p) {
    int e = p * 2048 + t * 8;
    int orow = e >> 6, ocol = e & 63;
    bf16x8 o;
#pragma unroll
    for (int i = 0; i < 8; ++i) o[i] = tile[ocol + i][orow];
    *(bf16x8*)(VT + (size_t)(c0 + orow) * MX + r0 + ocol) = o;
  }
}

// ---------------------------------------------------------------------------
// Flash attention + adapter. Balanced: each block owns q-tiles {qt, 15-qt}
// (exactly 34 kv-tiles per block). K/V double-buffered in LDS with counted
// vmcnt(8) (loads for t+1 stay in flight across compute of t). Swapped QK^T
// -> in-lane softmax (2 shfl levels). grid: (8 pairs, 32 heads, 2 batch),
// 256 threads = 4 waves x 32 q-rows; 80KB LDS -> 2 blocks/CU.
__global__ __launch_bounds__(256) void attn_kernel(const __bf16* __restrict__ Q,
                                                   const __bf16* __restrict__ K,
                                                   const __bf16* __restrict__ VT,
                                                   const float* __restrict__ gate,
                                                   __bf16* __restrict__ Out) {
  __shared__ __bf16 Ks[2][64 * 128];   // [kv][d] swizzled 16B chunks
  __shared__ __bf16 Vs[2][128 * 64];   // [d][kv] swizzled
  __shared__ __bf16 Ps[4][32 * 64];    // per-wave P

  const int tid = threadIdx.x;
  const int wv = tid >> 6, ln = tid & 63;
  const int lg = ln >> 4, lr = ln & 15;
  const int h = blockIdx.y, b = blockIdx.z;
  const float scale = 0.08838834764831845f;   // 1/sqrt(128)
  const float g = tanhf(gate[h]);

  // stage kv-tile t into buffer buf: 8 VMEM ops per thread (4 K + 4 V)
  auto stage = [&](int t, int buf) {
    const int kv0 = t * 64;
#pragma unroll
    for (int j = 0; j < 4; ++j) {
      int c = wv * 256 + j * 64 + ln;
      int rk = c >> 4, sck = (c & 15) ^ (rk & 7);
      gload_lds16(K + (size_t)(b * SEQ + kv0 + rk) * D + h * 128 + sck * 8,
                  Ks[buf] + (wv * 256 + j * 64) * 8);
      int rv = c >> 3, scv = (c & 7) ^ (rv & 7);
      gload_lds16(VT + (size_t)(h * 128 + rv) * MX + b * SEQ + kv0 + scv * 8,
                  Vs[buf] + (wv * 256 + j * 64) * 8);
    }
  };

  auto run_supertile = [&](int qt) {
    const int q0 = qt * 128;
    const int qbase = b * SEQ + q0 + wv * 32;

    // Q fragments: [mi][kd] (these 8 VMEM loads precede stage(0) in vmcnt order)
    bf16x8 qf[2][4];
#pragma unroll
    for (int mi = 0; mi < 2; ++mi)
#pragma unroll
      for (int kd = 0; kd < 4; ++kd)
        qf[mi][kd] = *(const bf16x8*)(Q + (size_t)(qbase + mi * 16 + lr) * D +
                                      h * 128 + kd * 32 + lg * 8);

    f32x4 O[2][8] = {};
    float mI2[2], lI2[2];
#pragma unroll
    for (int mi = 0; mi < 2; ++mi) { mI2[mi] = -1e30f; lI2[mi] = 0.f; }

    const int ntiles = 2 * qt + 2;
    stage(0, 0);

    for (int t = 0; t < ntiles; ++t) {
      const int cur = t & 1;
      const int kv0 = t * 64;
      if (t + 1 < ntiles) {
        stage(t + 1, cur ^ 1);
        asm volatile("s_waitcnt vmcnt(8)" ::: "memory");  // tile t's loads done
      } else {
        asm volatile("s_waitcnt vmcnt(0)" ::: "memory");
      }
      __builtin_amdgcn_s_barrier();
      __builtin_amdgcn_sched_barrier(0);

      // ---- QK^T swapped: S[mi][nf] holds S^T fragment
      // lane: q = q0+wv*32+mi*16+lr (col), kv = kv0+nf*16+lg*4+j (row j)
      f32x4 S[2][4] = {};
      __builtin_amdgcn_s_setprio(1);
#pragma unroll
      for (int kd = 0; kd < 4; ++kd) {
        bf16x8 kf[4];
#pragma unroll
        for (int nf = 0; nf < 4; ++nf) {
          int kr = nf * 16 + lr;
          kf[nf] = *(const bf16x8*)(Ks[cur] + kr * 128 +
                                    (((kd * 4 + lg) ^ (kr & 7)) * 8));
        }
#pragma unroll
        for (int mi = 0; mi < 2; ++mi)
#pragma unroll
          for (int nf = 0; nf < 4; ++nf)
            S[mi][nf] = mfma16(kf[nf], qf[mi][kd], S[mi][nf]);
      }
      __builtin_amdgcn_s_setprio(0);

      // ---- in-lane softmax
      float r2[2]; int grew = 0;
#pragma unroll
      for (int mi = 0; mi < 2; ++mi) {
        const int qg = q0 + wv * 32 + mi * 16 + lr;
        float mo = mI2[mi];
        float mt = -3e38f;
#pragma unroll
        for (int nf = 0; nf < 4; ++nf)
#pragma unroll
          for (int j = 0; j < 4; ++j) {
            int kvg = kv0 + nf * 16 + lg * 4 + j;
            float s = S[mi][nf][j] * scale;
            s = (kvg > qg) ? -1e30f : s;
            S[mi][nf][j] = s;
            mt = fmaxf(mt, s);
          }
        mt = fmaxf(mt, __shfl_xor(mt, 16));
        mt = fmaxf(mt, __shfl_xor(mt, 32));
        float mn = fmaxf(mo, mt);
        float ps = 0.f;
#pragma unroll
        for (int nf = 0; nf < 4; ++nf)
#pragma unroll
          for (int j = 0; j < 4; ++j) {
            float p = __expf(S[mi][nf][j] - mn);
            S[mi][nf][j] = p;
            ps += p;
          }
        ps += __shfl_xor(ps, 16);
        ps += __shfl_xor(ps, 32);
        float r = __expf(mo - mn);
        lI2[mi] = lI2[mi] * r + ps;
        mI2[mi] = mn;
        r2[mi] = r;
        grew |= (mn > mo) ? 1 : 0;
      }
      if (__any(grew)) {
#pragma unroll
        for (int mi = 0; mi < 2; ++mi)
#pragma unroll
          for (int j = 0; j < 4; ++j) {
            float rj = __shfl(r2[mi], lg * 4 + j);
#pragma unroll
            for (int n = 0; n < 8; ++n) O[mi][n][j] *= rj;
          }
      }

      // ---- P -> bf16 pairs -> per-wave LDS (no barrier: same-wave)
#pragma unroll
      for (int mi = 0; mi < 2; ++mi) {
        int q = mi * 16 + lr;
#pragma unroll
        for (int nf = 0; nf < 4; ++nf)
#pragma unroll
          for (int jj = 0; jj < 2; ++jj) {
            int kv = nf * 16 + lg * 4 + 2 * jj;
            bf16x2 pk;
            pk[0] = (__bf16)S[mi][nf][2 * jj];
            pk[1] = (__bf16)S[mi][nf][2 * jj + 1];
            *(bf16x2*)(Ps[wv] + q * 64 + (((kv >> 3) ^ (q & 7)) * 8) + (kv & 7)) = pk;
          }
      }

      // ---- PV
      __builtin_amdgcn_s_setprio(1);
#pragma unroll
      for (int kkv = 0; kkv < 2; ++kkv) {
        bf16x8 pf[2];
#pragma unroll
        for (int mi = 0; mi < 2; ++mi) {
          int prw = mi * 16 + lr;
          pf[mi] = *(const bf16x8*)(Ps[wv] + prw * 64 +
                                    (((kkv * 4 + lg) ^ (prw & 7)) * 8));
        }
#pragma unroll
        for (int n = 0; n < 8; ++n) {
          int vr = n * 16 + lr;
          bf16x8 vf = *(const bf16x8*)(Vs[cur] + vr * 64 +
                                       (((kkv * 4 + lg) ^ (vr & 7)) * 8));
#pragma unroll
          for (int mi = 0; mi < 2; ++mi) O[mi][n] = mfma16(pf[mi], vf, O[mi][n]);
        }
      }
      __builtin_amdgcn_s_setprio(0);

      __builtin_amdgcn_s_barrier();          // buf reuse fence
      __builtin_amdgcn_sched_barrier(0);
    }

    // ---- normalize
#pragma unroll
    for (int mi = 0; mi < 2; ++mi) {
      float inv = 1.0f / lI2[mi];
#pragma unroll
      for (int j = 0; j < 4; ++j) {
        float invj = __shfl(inv, lg * 4 + j);
#pragma unroll
        for (int n = 0; n < 8; ++n) O[mi][n][j] *= invj;
      }
    }

    // ---- adapter branch (direct global fragments; 10 kv rows + zero pad)
    {
      f32x4 Sa[2] = {};
#pragma unroll
      for (int kd = 0; kd < 4; ++kd) {
        bf16x8 kfa = *(const bf16x8*)(K + (size_t)(2 * SEQ + lr) * D +
                                      h * 128 + kd * 32 + lg * 8);
#pragma unroll
        for (int mi = 0; mi < 2; ++mi) Sa[mi] = mfma16(kfa, qf[mi][kd], Sa[mi]);
      }
#pragma unroll
      for (int mi = 0; mi < 2; ++mi) {
        float mt = -3e38f;
#pragma unroll
        for (int j = 0; j < 4; ++j) {
          int kv = lg * 4 + j;
          float s = Sa[mi][j] * scale;
          s = (kv >= 10) ? -1e30f : s;
          Sa[mi][j] = s;
          mt = fmaxf(mt, s);
        }
        mt = fmaxf(mt, __shfl_xor(mt, 16));
        mt = fmaxf(mt, __shfl_xor(mt, 32));
        float ps = 0.f;
#pragma unroll
        for (int j = 0; j < 4; ++j) {
          float p = __expf(Sa[mi][j] - mt);
          Sa[mi][j] = p;
          ps += p;
        }
        ps += __shfl_xor(ps, 16);
        ps += __shfl_xor(ps, 32);
        float gs = g / ps;
        int q = mi * 16 + lr;
#pragma unroll
        for (int jj = 0; jj < 2; ++jj) {
          int kv = lg * 4 + 2 * jj;
          bf16x2 pk;
          pk[0] = (__bf16)(Sa[mi][2 * jj] * gs);
          pk[1] = (__bf16)(Sa[mi][2 * jj + 1] * gs);
          *(bf16x2*)(Ps[wv] + q * 64 + (((kv >> 3) ^ (q & 7)) * 8) + (kv & 7)) = pk;
          int kv2 = 16 + kv;
          bf16x2 z = {};
          *(bf16x2*)(Ps[wv] + q * 64 + (((kv2 >> 3) ^ (q & 7)) * 8) + (kv2 & 7)) = z;
        }
      }
      bf16x8 pfa[2];
#pragma unroll
      for (int mi = 0; mi < 2; ++mi) {
        int prw = mi * 16 + lr;
        pfa[mi] = *(const bf16x8*)(Ps[wv] + prw * 64 + ((lg ^ (prw & 7)) * 8));
      }
#pragma unroll
      for (int n = 0; n < 8; ++n) {
        bf16x8 vfa = *(const bf16x8*)(VT + (size_t)(h * 128 + n * 16 + lr) * MX +
                                      2 * SEQ + lg * 8);
#pragma unroll
        for (int mi = 0; mi < 2; ++mi) O[mi][n] = mfma16(pfa[mi], vfa, O[mi][n]);
      }
    }

    // ---- write out
#pragma unroll
    for (int mi = 0; mi < 2; ++mi)
#pragma unroll
      for (int n = 0; n < 8; ++n)
#pragma unroll
        for (int j = 0; j < 4; ++j)
          Out[(size_t)(qbase + mi * 16 + lg * 4 + j) * D + h * 128 + n * 16 + lr] =
              (__bf16)O[mi][n][j];
  };

  run_supertile(15 - blockIdx.x);   // heavy first
  run_supertile(blockIdx.x);
}

// ---------------------------------------------------------------------------
extern "C" void kernel_launch(void* const* d_in, const int* in_sizes, int n_in,
                              void* d_out, int out_size, void* d_ws, size_t ws_size,
                              hipStream_t stream) {
  const float* x    = (const float*)d_in[0];
  const float* wq   = (const float*)d_in[1];
  const float* wk   = (const float*)d_in[2];
  const float* wv   = (const float*)d_in[3];
  const float* wo   = (const float*)d_in[4];
  const float* gate = (const float*)d_in[5];
  const float* ad   = (const float*)d_in[6];
  const float* fc   = (const float*)d_in[7];
  const float* fs   = (const float*)d_in[8];

  const size_t WSZ = (size_t)D * D * 2;     // 33,554,432
  const size_t XSZ = (size_t)MX * D * 2;    // 34,603,008
  if (ws_size < 4 * WSZ + XSZ + WSZ + 3 * XSZ) return;  // 306,184,192 needed

  char* w = (char*)d_ws;
  size_t off = 0;
  auto alloc = [&](size_t sz) { void* p = w + off; off += sz; return p; };
  __bf16* wqT = (__bf16*)alloc(WSZ);
  __bf16* wkT = (__bf16*)alloc(WSZ);
  __bf16* wvT = (__bf16*)alloc(WSZ);
  __bf16* woT = (__bf16*)alloc(WSZ);
  __bf16* xa  = (__bf16*)alloc(XSZ);
  __bf16* qb  = (__bf16*)alloc(WSZ);
  __bf16* kb  = (__bf16*)alloc(XSZ);
  __bf16* vb  = (__bf16*)alloc(XSZ);
  __bf16* vT  = (__bf16*)alloc(XSZ);
  __bf16* attn = vb;   // vb dead after transpose_v; reuse as attention output

  dim3 blk(256);
  transpose_cast<<<dim3(64, 64), blk, 0, stream>>>(wq, wqT);
  transpose_cast<<<dim3(64, 64), blk, 0, stream>>>(wk, wkT);
  transpose_cast<<<dim3(64, 64), blk, 0, stream>>>(wv, wvT);
  transpose_cast<<<dim3(64, 64), blk, 0, stream>>>(wo, woT);
  build_xa<<<dim3(16896), blk, 0, stream>>>(x, ad, xa);

  gemm_bt<false><<<dim3(32, 32), blk, 0, stream>>>(xa, wqT, qb);
  gemm_bt<false><<<dim3(33, 32), blk, 0, stream>>>(xa, wkT, kb);
  gemm_bt<false><<<dim3(33, 32), blk, 0, stream>>>(xa, wvT, vb);

  rope_kernel<<<dim3(4096, 2), blk, 0, stream>>>(qb, kb, fc, fs);
  transpose_v<<<dim3(66, 64), blk, 0, stream>>>(vb, vT);

  attn_kernel<<<dim3(8, 32, 2), blk, 0, stream>>>(qb, kb, vT, gate, attn);

  gemm_bt<true><<<dim3(32, 32), blk, 0, stream>>>(attn, woT, d_out);
}